// Round 3
// baseline (2040.012 us; speedup 1.0000x reference)
//
#include <hip/hip_runtime.h>

#define BT     32768
#define HIDDEN 512
#define DDIM   256
#define KCODE  1024
#define NQUANT 8

typedef _Float16 f16;
typedef _Float16 f16x8 __attribute__((ext_vector_type(8)));
typedef float f32x4 __attribute__((ext_vector_type(4)));
typedef float f32x8 __attribute__((ext_vector_type(8)));

#define LO_SCALE 64.0f
#define LO_INV   0.015625f

// ---------------------------------------------------------------------------
// cnorm: ||c||^2 for every code of every quantizer (fp32 exact)
// ---------------------------------------------------------------------------
__global__ __launch_bounds__(256) void cnorm_kernel(const float* __restrict__ cb,
                                                    float* __restrict__ cnorm) {
  __shared__ float red[256];
  const int code = blockIdx.x;
  const float v = cb[(size_t)code * DDIM + threadIdx.x];
  red[threadIdx.x] = v * v;
  __syncthreads();
  for (int s = 128; s > 0; s >>= 1) {
    if (threadIdx.x < s) red[threadIdx.x] += red[threadIdx.x + s];
    __syncthreads();
  }
  if (threadIdx.x == 0) cnorm[code] = red[0];
}

// ---------------------------------------------------------------------------
// codebook -> f16 hi/lo ext: cbext[c][0..255]=hi, [256..511]=lo*64
// ---------------------------------------------------------------------------
__global__ __launch_bounds__(256) void cbext_conv(const float* __restrict__ cb,
                                                  f16* __restrict__ cbext) {
  const int idx = blockIdx.x * 256 + threadIdx.x;
  const int c = idx >> 8, d = idx & 255;
  const float v = cb[idx];
  const f16 hi = (f16)v;
  cbext[(size_t)c * 512 + d] = hi;
  cbext[(size_t)c * 512 + 256 + d] = (f16)((v - (float)hi) * LO_SCALE);
}

// ---------------------------------------------------------------------------
// weight -> f16 hi/lo ext: Wext[n][0..K-1]=hi, [K..2K-1]=lo*64
// ---------------------------------------------------------------------------
__global__ __launch_bounds__(256) void bext_conv(const float* __restrict__ W,
                                                 f16* __restrict__ Wext,
                                                 int N, int K) {
  const int idx = blockIdx.x * 256 + threadIdx.x;
  if (idx >= N * K) return;
  const int n = idx / K, k = idx - n * K;
  const float v = W[idx];
  const f16 hi = (f16)v;
  Wext[(size_t)n * 2 * K + k] = hi;
  Wext[(size_t)n * 2 * K + K + k] = (f16)((v - (float)hi) * LO_SCALE);
}

// ---------------------------------------------------------------------------
// RVQ step v3: A (residual hi|lo) in VGPR fragments, B direct-from-global
// (L1/L2 resident), zero barriers in the K-loop, register running argmin.
// Block = 128 tokens, 8 waves (wr 0..3 token-tiles of 32, wc 0..1 code-halves).
// Per chunk (128 codes): t 0-3 hi_r*lo_c, t 4-7 lo_r*hi_c, acc*=1/64,
// t 8-11 hi_r*hi_c.  d = ||c||^2 - 2*dot (||r||^2 dropped, argmin-safe).
// ---------------------------------------------------------------------------
__global__ __launch_bounds__(512, 2) void rvq_v3(
    f16* __restrict__ rext, const f16* __restrict__ cbext,
    const float* __restrict__ cbf32, const float* __restrict__ cnormq,
    float* __restrict__ qsum, float* __restrict__ q1, float* __restrict__ q2,
    float* __restrict__ commitAcc, int nq) {
  __shared__ float mv[2][128];
  __shared__ int   mi[2][128];
  __shared__ int   bidx[128];
  __shared__ float redc[512];
  const int tid = threadIdx.x;
  const int w = tid >> 6, l = tid & 63;
  const int wr = w >> 1, wc = w & 1;
  const int lj = l & 15, li = l >> 4;
  const int m0 = blockIdx.x * 128;

  // A fragments: 16 slices of 32 f16 per m-tile (hi = slices 0-7, lo = 8-15)
  f16x8 af[2][16];
#pragma unroll
  for (int m = 0; m < 2; ++m) {
    const int row = m0 + wr * 32 + m * 16 + lj;
#pragma unroll
    for (int s = 0; s < 16; ++s)
      af[m][s] = *(const f16x8*)&rext[(size_t)row * 512 + s * 32 + li * 8];
  }

  float bval[2][4]; int bidxr[2][4];
#pragma unroll
  for (int m = 0; m < 2; ++m)
#pragma unroll
    for (int j = 0; j < 4; ++j) { bval[m][j] = 3.0e38f; bidxr[m][j] = 0; }

  for (int chunk = 0; chunk < 8; ++chunk) {
    const f16* cbc = cbext + (size_t)chunk * 128 * 512;
    f32x4 acc[2][4];
#pragma unroll
    for (int m = 0; m < 2; ++m)
#pragma unroll
      for (int n = 0; n < 4; ++n) acc[m][n] = (f32x4){0.f, 0.f, 0.f, 0.f};

#pragma unroll
    for (int t = 0; t < 12; ++t) {
      const int tl = (t < 4) ? t : (t < 8 ? t - 4 : t - 8);
      const int kB = (t < 4) ? (256 + tl * 64) : (tl * 64);  // lo_c | hi_c | hi_c
      f16x8 bf[4][2];
#pragma unroll
      for (int n = 0; n < 4; ++n) {
        const int code = wc * 64 + n * 16 + lj;
#pragma unroll
        for (int kk = 0; kk < 2; ++kk)
          bf[n][kk] = *(const f16x8*)&cbc[(size_t)code * 512 + kB + kk * 32 + li * 8];
      }
#pragma unroll
      for (int m = 0; m < 2; ++m)
#pragma unroll
        for (int n = 0; n < 4; ++n)
#pragma unroll
          for (int kk = 0; kk < 2; ++kk) {
            const int as = (t < 8 && t >= 4) ? (8 + 2 * tl + kk) : (2 * tl + kk);
            acc[m][n] = __builtin_amdgcn_mfma_f32_16x16x32_f16(af[m][as], bf[n][kk], acc[m][n], 0, 0, 0);
          }
      if (t == 7) {  // cross terms complete: rescale before hi*hi
#pragma unroll
        for (int m = 0; m < 2; ++m)
#pragma unroll
          for (int n = 0; n < 4; ++n)
#pragma unroll
            for (int j = 0; j < 4; ++j) acc[m][n][j] *= LO_INV;
      }
    }
    // distances + running register argmin (strict <, ascending order)
#pragma unroll
    for (int n = 0; n < 4; ++n) {
      const int cl = chunk * 128 + wc * 64 + n * 16 + lj;
      const float cn = cnormq[cl];
#pragma unroll
      for (int m = 0; m < 2; ++m)
#pragma unroll
        for (int j = 0; j < 4; ++j) {
          const float d = cn - 2.0f * acc[m][n][j];
          if (d < bval[m][j]) { bval[m][j] = d; bidxr[m][j] = cl; }
        }
    }
  }

  // reduce over the 16-lane code axis (lexicographic (val, idx) min)
#pragma unroll
  for (int off = 1; off < 16; off <<= 1) {
#pragma unroll
    for (int m = 0; m < 2; ++m)
#pragma unroll
      for (int j = 0; j < 4; ++j) {
        const float ov = __shfl_xor(bval[m][j], off);
        const int oi = __shfl_xor(bidxr[m][j], off);
        if (ov < bval[m][j] || (ov == bval[m][j] && oi < bidxr[m][j])) {
          bval[m][j] = ov; bidxr[m][j] = oi;
        }
      }
  }
  if (lj == 0) {
#pragma unroll
    for (int m = 0; m < 2; ++m)
#pragma unroll
      for (int j = 0; j < 4; ++j) {
        const int tok = wr * 32 + m * 16 + li * 4 + j;
        mv[wc][tok] = bval[m][j]; mi[wc][tok] = bidxr[m][j];
      }
  }
  __syncthreads();
  if (tid < 128) {
    float v0 = mv[0][tid]; int i0 = mi[0][tid];
    if (mv[1][tid] < v0) { v0 = mv[1][tid]; i0 = mi[1][tid]; }
    bidx[tid] = i0;
  }
  __syncthreads();

  // epilogue: gather + commit + residual update (thread = dim x token-half)
  float csum = 0.f;
  const int d = tid & 255, th = tid >> 8;
  for (int tk = 0; tk < 64; ++tk) {
    const int tok = th * 64 + tk;
    const int code = bidx[tok];
    const float qv = cbf32[(size_t)code * DDIM + d];
    const size_t rbase = (size_t)(m0 + tok) * 512;
    const float rold = (float)rext[rbase + d] + (float)rext[rbase + 256 + d] * LO_INV;
    const float diff = qv - rold;
    csum += diff * diff;
    const float rnew = rold - qv;
    const f16 nh = (f16)rnew;
    rext[rbase + d] = nh;
    rext[rbase + 256 + d] = (f16)((rnew - (float)nh) * LO_SCALE);
    const size_t gi = (size_t)(m0 + tok) * DDIM + d;
    if (nq == 0)      { qsum[gi] = qv;  q1[gi] = qv; }
    else if (nq == 1) { qsum[gi] += qv; q2[gi] = qv; }
    else              { qsum[gi] += qv; }
  }
  redc[tid] = csum;
  __syncthreads();
  for (int s = 256; s > 0; s >>= 1) {
    if (tid < s) redc[tid] += redc[tid + s];
    __syncthreads();
  }
  if (tid == 0) atomicAdd(commitAcc, redc[0]);
}

// ---------------------------------------------------------------------------
// MFMA projection: C[M][N] = A[M][K](f32) . Bext^T + bias, hi/lo split.
// Same structure as rvq_v3: A-frags converted f32->hi/lo in registers,
// B direct-from-global (Wext is L2-resident). K processed in panels of 256.
// WEXT: write f16 hi/lo into rext (proj_in); else write f32 (proj_out).
// ---------------------------------------------------------------------------
template <int K, bool WEXT>
__global__ __launch_bounds__(512, 2) void proj_mfma(
    const float* __restrict__ A, const f16* __restrict__ Bext,
    const float* __restrict__ bias, float* __restrict__ Cout,
    f16* __restrict__ CextOut, int Ntot) {
  const int tid = threadIdx.x;
  const int w = tid >> 6, l = tid & 63;
  const int wr = w >> 1, wc = w & 1;
  const int lj = l & 15, li = l >> 4;
  const int m0 = blockIdx.x * 128;
  const int n0 = blockIdx.y * 128;

  f32x4 acc[2][4], acc2[2][4];
#pragma unroll
  for (int m = 0; m < 2; ++m)
#pragma unroll
    for (int n = 0; n < 4; ++n) {
      acc[m][n] = (f32x4){0.f, 0.f, 0.f, 0.f};
      acc2[m][n] = (f32x4){0.f, 0.f, 0.f, 0.f};
    }

#pragma unroll 1
  for (int p = 0; p < K / 256; ++p) {
    f16x8 ahi[2][8], alo[2][8];
#pragma unroll
    for (int m = 0; m < 2; ++m) {
      const int row = m0 + wr * 32 + m * 16 + lj;
#pragma unroll
      for (int s = 0; s < 8; ++s) {
        const f32x8 v = *(const f32x8*)&A[(size_t)row * K + p * 256 + s * 32 + li * 8];
        f16x8 h, lo;
#pragma unroll
        for (int i = 0; i < 8; ++i) {
          const f16 hh = (f16)v[i];
          h[i] = hh;
          lo[i] = (f16)((v[i] - (float)hh) * LO_SCALE);
        }
        ahi[m][s] = h; alo[m][s] = lo;
      }
    }
#pragma unroll
    for (int t = 0; t < 12; ++t) {
      const int tl = (t < 4) ? t : (t < 8 ? t - 4 : t - 8);
      const int kB = (t < 4) ? (K + p * 256 + tl * 64) : (p * 256 + tl * 64);
      f16x8 bf[4][2];
#pragma unroll
      for (int n = 0; n < 4; ++n) {
        const int nrow = n0 + wc * 64 + n * 16 + lj;
#pragma unroll
        for (int kk = 0; kk < 2; ++kk)
          bf[n][kk] = *(const f16x8*)&Bext[(size_t)nrow * (2 * K) + kB + kk * 32 + li * 8];
      }
#pragma unroll
      for (int m = 0; m < 2; ++m)
#pragma unroll
        for (int n = 0; n < 4; ++n)
#pragma unroll
          for (int kk = 0; kk < 2; ++kk) {
            if (t < 4)
              acc2[m][n] = __builtin_amdgcn_mfma_f32_16x16x32_f16(ahi[m][2 * tl + kk], bf[n][kk], acc2[m][n], 0, 0, 0);
            else if (t < 8)
              acc2[m][n] = __builtin_amdgcn_mfma_f32_16x16x32_f16(alo[m][2 * tl + kk], bf[n][kk], acc2[m][n], 0, 0, 0);
            else
              acc[m][n] = __builtin_amdgcn_mfma_f32_16x16x32_f16(ahi[m][2 * tl + kk], bf[n][kk], acc[m][n], 0, 0, 0);
          }
    }
  }

#pragma unroll
  for (int m = 0; m < 2; ++m)
#pragma unroll
    for (int n = 0; n < 4; ++n) {
      const int ncol = n0 + wc * 64 + n * 16 + lj;
      const float bb = bias[ncol];
#pragma unroll
      for (int j = 0; j < 4; ++j) {
        const int tok = m0 + wr * 32 + m * 16 + li * 4 + j;
        const float vv = acc[m][n][j] + acc2[m][n][j] * LO_INV + bb;
        if (WEXT) {
          const f16 hh = (f16)vv;
          CextOut[(size_t)tok * 512 + ncol] = hh;
          CextOut[(size_t)tok * 512 + 256 + ncol] = (f16)((vv - (float)hh) * LO_SCALE);
        } else {
          Cout[(size_t)tok * Ntot + ncol] = vv;
        }
      }
    }
}

__global__ void zero_one(float* p) { p[0] = 0.f; }

__global__ void finalize_com(const float* __restrict__ a, float* __restrict__ o) {
  o[0] = a[0] * (1.0f / (float)((size_t)NQUANT * BT * DDIM));
}

extern "C" void kernel_launch(void* const* d_in, const int* in_sizes, int n_in,
                              void* d_out, int out_size, void* d_ws, size_t ws_size,
                              hipStream_t stream) {
  (void)in_sizes; (void)n_in; (void)out_size; (void)ws_size;
  const float* x     = (const float*)d_in[0];
  const float* W_in  = (const float*)d_in[1];
  const float* b_in  = (const float*)d_in[2];
  const float* W_out = (const float*)d_in[3];
  const float* b_out = (const float*)d_in[4];
  const float* cbs   = (const float*)d_in[5];

  float* out = (float*)d_out;                        // [BT, HIDDEN]
  float* q1  = out + (size_t)BT * HIDDEN;            // [BT, DDIM]
  float* q2  = q1 + (size_t)BT * DDIM;               // [BT, DDIM]
  float* com = q2 + (size_t)BT * DDIM;               // [1]

  f16*   rext      = (f16*)d_ws;                          // [BT][512]  32 MB
  float* qsum      = (float*)(rext + (size_t)BT * 512);   // [BT][256]  32 MB
  f16*   cbext     = (f16*)(qsum + (size_t)BT * DDIM);    // [1024][512] 1 MB
  f16*   W_inext   = cbext + (size_t)KCODE * 512;         // [256][1024] 512 KB
  f16*   W_outext  = W_inext + (size_t)DDIM * 1024;       // [512][512]  512 KB
  float* cnorm     = (float*)(W_outext + (size_t)HIDDEN * 512);  // [NQ*K]
  float* commitAcc = cnorm + NQUANT * KCODE;

  cnorm_kernel<<<NQUANT * KCODE, 256, 0, stream>>>(cbs, cnorm);
  bext_conv<<<(DDIM * HIDDEN + 255) / 256, 256, 0, stream>>>(W_in, W_inext, DDIM, HIDDEN);
  bext_conv<<<(HIDDEN * DDIM + 255) / 256, 256, 0, stream>>>(W_out, W_outext, HIDDEN, DDIM);
  proj_mfma<HIDDEN, true><<<dim3(BT / 128, 2), 512, 0, stream>>>(
      x, W_inext, b_in, nullptr, rext, DDIM);
  zero_one<<<1, 1, 0, stream>>>(commitAcc);
  for (int nq = 0; nq < NQUANT; ++nq) {
    const float* cbq = cbs + (size_t)nq * KCODE * DDIM;
    cbext_conv<<<KCODE, 256, 0, stream>>>(cbq, cbext);
    rvq_v3<<<BT / 128, 512, 0, stream>>>(rext, cbext, cbq, cnorm + nq * KCODE,
                                         qsum, q1, q2, commitAcc, nq);
  }
  proj_mfma<DDIM, false><<<dim3(BT / 128, 4), 512, 0, stream>>>(
      qsum, W_outext, b_out, out, nullptr, HIDDEN);
  finalize_com<<<1, 1, 0, stream>>>(commitAcc, com);
}

// Round 4
// 1994.587 us; speedup vs baseline: 1.0228x; 1.0228x over previous
//
#include <hip/hip_runtime.h>

#define BT     32768
#define HIDDEN 512
#define DDIM   256
#define KCODE  1024
#define NQUANT 8

typedef _Float16 f16;
typedef _Float16 f16x8 __attribute__((ext_vector_type(8)));
typedef float f32x4 __attribute__((ext_vector_type(4)));
typedef float f32x8 __attribute__((ext_vector_type(8)));

#define LO_SCALE 64.0f
#define LO_INV   0.015625f

// ---------------------------------------------------------------------------
// cnorm: ||c||^2 for all NQ*K codes (fp32 exact)
// ---------------------------------------------------------------------------
__global__ __launch_bounds__(256) void cnorm_kernel(const float* __restrict__ cb,
                                                    float* __restrict__ cnorm) {
  __shared__ float red[256];
  const int code = blockIdx.x;
  const float v = cb[(size_t)code * DDIM + threadIdx.x];
  red[threadIdx.x] = v * v;
  __syncthreads();
  for (int s = 128; s > 0; s >>= 1) {
    if (threadIdx.x < s) red[threadIdx.x] += red[threadIdx.x + s];
    __syncthreads();
  }
  if (threadIdx.x == 0) cnorm[code] = red[0];
}

// ---------------------------------------------------------------------------
// all codebooks -> f16 hi/lo ext: cbext[c][0..255]=hi, [256..511]=lo*64
// grid = NQ*K blocks x 256
// ---------------------------------------------------------------------------
__global__ __launch_bounds__(256) void cbext_conv(const float* __restrict__ cb,
                                                  f16* __restrict__ cbext) {
  const size_t idx = (size_t)blockIdx.x * 256 + threadIdx.x;
  const size_t c = idx >> 8;
  const int d = (int)(idx & 255);
  const float v = cb[idx];
  const f16 hi = (f16)v;
  cbext[c * 512 + d] = hi;
  cbext[c * 512 + 256 + d] = (f16)((v - (float)hi) * LO_SCALE);
}

// ---------------------------------------------------------------------------
// weight -> f16 hi/lo ext: Wext[n][0..K-1]=hi, [K..2K-1]=lo*64
// ---------------------------------------------------------------------------
__global__ __launch_bounds__(256) void bext_conv(const float* __restrict__ W,
                                                 f16* __restrict__ Wext,
                                                 int N, int K) {
  const int idx = blockIdx.x * 256 + threadIdx.x;
  if (idx >= N * K) return;
  const int n = idx / K, k = idx - n * K;
  const float v = W[idx];
  const f16 hi = (f16)v;
  Wext[(size_t)n * 2 * K + k] = hi;
  Wext[(size_t)n * 2 * K + K + k] = (f16)((v - (float)hi) * LO_SCALE);
}

// ---------------------------------------------------------------------------
// Fused 8-step RVQ. Block = 128 tokens, 8 waves (wr 0..3 x wc 0..1).
// Residual lives in af[2][16] registers for the entire cascade.
// Per step: sweep 1024 codes (8 chunks x 12 t-steps of 16x16x32 MFMA,
// hi/lo split: t0-3 lo_c*hi_r, t4-7 hi_c*lo_r, rescale, t8-11 hi_c*hi_r),
// register argmin -> LDS merge -> in-register residual update (exact f32
// code gather). qsum = h - r_final at the end; commit in registers.
// ---------------------------------------------------------------------------
__global__ __launch_bounds__(512, 2) void rvq_fused(
    const f16* __restrict__ rext, const f16* __restrict__ cbext,
    const float* __restrict__ cbf32, const float* __restrict__ cnorm,
    float* __restrict__ qsum, float* __restrict__ q1, float* __restrict__ q2,
    float* __restrict__ commitAcc) {
  __shared__ float mv[2][128];
  __shared__ int   mi[2][128];
  __shared__ int   bidx[128];
  __shared__ float redc[512];
  const int tid = threadIdx.x;
  const int w = tid >> 6, l = tid & 63;
  const int wr = w >> 1, wc = w & 1;
  const int lj = l & 15, li = l >> 4;
  const int m0 = blockIdx.x * 128;

  // residual fragments: slices 0-7 = hi (d = s*32+li*8), 8-15 = lo
  f16x8 af[2][16];
#pragma unroll
  for (int m = 0; m < 2; ++m) {
    const int row = m0 + wr * 32 + m * 16 + lj;
#pragma unroll
    for (int s = 0; s < 16; ++s)
      af[m][s] = *(const f16x8*)&rext[(size_t)row * 512 + s * 32 + li * 8];
  }

  float csum = 0.f;

#pragma unroll 1
  for (int nq = 0; nq < NQUANT; ++nq) {
    const f16* cbq = cbext + (size_t)nq * KCODE * 512;
    const float* cnq = cnorm + nq * KCODE;
    float bval[2][4]; int bidxr[2][4];
#pragma unroll
    for (int m = 0; m < 2; ++m)
#pragma unroll
      for (int j = 0; j < 4; ++j) { bval[m][j] = 3.0e38f; bidxr[m][j] = 0; }

#pragma unroll 1
    for (int chunk = 0; chunk < 8; ++chunk) {
      const f16* cbc = cbq + (size_t)chunk * 128 * 512;
      f32x4 acc[2][4];
#pragma unroll
      for (int m = 0; m < 2; ++m)
#pragma unroll
        for (int n = 0; n < 4; ++n) acc[m][n] = (f32x4){0.f, 0.f, 0.f, 0.f};

#pragma unroll
      for (int t = 0; t < 12; ++t) {
        const int tl = (t < 4) ? t : (t < 8 ? t - 4 : t - 8);
        const int kB = (t < 4) ? (256 + tl * 64) : (tl * 64);
        f16x8 bf[4][2];
#pragma unroll
        for (int n = 0; n < 4; ++n) {
          const int code = wc * 64 + n * 16 + lj;
#pragma unroll
          for (int kk = 0; kk < 2; ++kk)
            bf[n][kk] = *(const f16x8*)&cbc[(size_t)code * 512 + kB + kk * 32 + li * 8];
        }
#pragma unroll
        for (int m = 0; m < 2; ++m)
#pragma unroll
          for (int n = 0; n < 4; ++n)
#pragma unroll
            for (int kk = 0; kk < 2; ++kk) {
              const int as = (t >= 4 && t < 8) ? (8 + 2 * tl + kk) : (2 * tl + kk);
              acc[m][n] = __builtin_amdgcn_mfma_f32_16x16x32_f16(af[m][as], bf[n][kk], acc[m][n], 0, 0, 0);
            }
        if (t == 7) {
#pragma unroll
          for (int m = 0; m < 2; ++m)
#pragma unroll
            for (int n = 0; n < 4; ++n)
#pragma unroll
              for (int j = 0; j < 4; ++j) acc[m][n][j] *= LO_INV;
        }
      }
#pragma unroll
      for (int n = 0; n < 4; ++n) {
        const int cl = chunk * 128 + wc * 64 + n * 16 + lj;
        const float cn = cnq[cl];
#pragma unroll
        for (int m = 0; m < 2; ++m)
#pragma unroll
          for (int j = 0; j < 4; ++j) {
            const float d = cn - 2.0f * acc[m][n][j];
            if (d < bval[m][j]) { bval[m][j] = d; bidxr[m][j] = cl; }
          }
      }
    }

    // lane reduce over the 16-lane code axis
#pragma unroll
    for (int off = 1; off < 16; off <<= 1) {
#pragma unroll
      for (int m = 0; m < 2; ++m)
#pragma unroll
        for (int j = 0; j < 4; ++j) {
          const float ov = __shfl_xor(bval[m][j], off);
          const int oi = __shfl_xor(bidxr[m][j], off);
          if (ov < bval[m][j] || (ov == bval[m][j] && oi < bidxr[m][j])) {
            bval[m][j] = ov; bidxr[m][j] = oi;
          }
        }
    }
    if (lj == 0) {
#pragma unroll
      for (int m = 0; m < 2; ++m)
#pragma unroll
        for (int j = 0; j < 4; ++j) {
          const int tok = wr * 32 + m * 16 + li * 4 + j;
          mv[wc][tok] = bval[m][j]; mi[wc][tok] = bidxr[m][j];
        }
    }
    __syncthreads();
    if (tid < 128) {
      float v0 = mv[0][tid]; int i0 = mi[0][tid];
      if (mv[1][tid] < v0) { v0 = mv[1][tid]; i0 = mi[1][tid]; }
      bidx[tid] = i0;
    }
    __syncthreads();

    // in-register residual update + q1/q2 emission
#pragma unroll
    for (int m = 0; m < 2; ++m) {
      const int tok = wr * 32 + m * 16 + lj;
      const int code = bidx[tok];
      const float* qrow = cbf32 + ((size_t)nq * KCODE + code) * DDIM;
#pragma unroll
      for (int s = 0; s < 8; ++s) {
        const f32x8 qv = *(const f32x8*)&qrow[s * 32 + li * 8];
        f16x8 h = af[m][s], lo = af[m][8 + s];
#pragma unroll
        for (int i = 0; i < 8; ++i) {
          const float rold = (float)h[i] + (float)lo[i] * LO_INV;
          const float diff = qv[i] - rold;
          csum += diff * diff;
          const float rnew = rold - qv[i];
          const f16 nh = (f16)rnew;
          h[i] = nh;
          lo[i] = (f16)((rnew - (float)nh) * LO_SCALE);
        }
        af[m][s] = h; af[m][8 + s] = lo;
        if (wc == 0 && nq == 0)
          *(f32x8*)&q1[(size_t)(m0 + tok) * DDIM + s * 32 + li * 8] = qv;
        if (wc == 0 && nq == 1)
          *(f32x8*)&q2[(size_t)(m0 + tok) * DDIM + s * 32 + li * 8] = qv;
      }
    }
    __syncthreads();  // protect mv/mi/bidx for next step
  }

  // qsum = h - r_final (h re-read from untouched rext)
#pragma unroll
  for (int m = 0; m < 2; ++m) {
    const int row = m0 + wr * 32 + m * 16 + lj;
#pragma unroll
    for (int s = 0; s < 8; ++s) {
      const f16x8 hh = *(const f16x8*)&rext[(size_t)row * 512 + s * 32 + li * 8];
      const f16x8 hl = *(const f16x8*)&rext[(size_t)row * 512 + 256 + s * 32 + li * 8];
      f32x8 o;
#pragma unroll
      for (int i = 0; i < 8; ++i)
        o[i] = ((float)hh[i] + (float)hl[i] * LO_INV) -
               ((float)af[m][s][i] + (float)af[m][8 + s][i] * LO_INV);
      if (wc == 0)
        *(f32x8*)&qsum[(size_t)row * DDIM + s * 32 + li * 8] = o;
    }
  }

  redc[tid] = (wc == 0) ? csum : 0.f;
  __syncthreads();
  for (int s = 256; s > 0; s >>= 1) {
    if (tid < s) redc[tid] += redc[tid + s];
    __syncthreads();
  }
  if (tid == 0) atomicAdd(commitAcc, redc[0]);
}

// ---------------------------------------------------------------------------
// MFMA projection (unchanged from round 3): A f32 -> hi/lo in registers,
// B (Wext) direct-from-global. WEXT: write hi/lo f16 (proj_in) else f32.
// ---------------------------------------------------------------------------
template <int K, bool WEXT>
__global__ __launch_bounds__(512, 2) void proj_mfma(
    const float* __restrict__ A, const f16* __restrict__ Bext,
    const float* __restrict__ bias, float* __restrict__ Cout,
    f16* __restrict__ CextOut, int Ntot) {
  const int tid = threadIdx.x;
  const int w = tid >> 6, l = tid & 63;
  const int wr = w >> 1, wc = w & 1;
  const int lj = l & 15, li = l >> 4;
  const int m0 = blockIdx.x * 128;
  const int n0 = blockIdx.y * 128;

  f32x4 acc[2][4], acc2[2][4];
#pragma unroll
  for (int m = 0; m < 2; ++m)
#pragma unroll
    for (int n = 0; n < 4; ++n) {
      acc[m][n] = (f32x4){0.f, 0.f, 0.f, 0.f};
      acc2[m][n] = (f32x4){0.f, 0.f, 0.f, 0.f};
    }

#pragma unroll 1
  for (int p = 0; p < K / 256; ++p) {
    f16x8 ahi[2][8], alo[2][8];
#pragma unroll
    for (int m = 0; m < 2; ++m) {
      const int row = m0 + wr * 32 + m * 16 + lj;
#pragma unroll
      for (int s = 0; s < 8; ++s) {
        const f32x8 v = *(const f32x8*)&A[(size_t)row * K + p * 256 + s * 32 + li * 8];
        f16x8 h, lo;
#pragma unroll
        for (int i = 0; i < 8; ++i) {
          const f16 hh = (f16)v[i];
          h[i] = hh;
          lo[i] = (f16)((v[i] - (float)hh) * LO_SCALE);
        }
        ahi[m][s] = h; alo[m][s] = lo;
      }
    }
#pragma unroll
    for (int t = 0; t < 12; ++t) {
      const int tl = (t < 4) ? t : (t < 8 ? t - 4 : t - 8);
      const int kB = (t < 4) ? (K + p * 256 + tl * 64) : (p * 256 + tl * 64);
      f16x8 bf[4][2];
#pragma unroll
      for (int n = 0; n < 4; ++n) {
        const int nrow = n0 + wc * 64 + n * 16 + lj;
#pragma unroll
        for (int kk = 0; kk < 2; ++kk)
          bf[n][kk] = *(const f16x8*)&Bext[(size_t)nrow * (2 * K) + kB + kk * 32 + li * 8];
      }
#pragma unroll
      for (int m = 0; m < 2; ++m)
#pragma unroll
        for (int n = 0; n < 4; ++n)
#pragma unroll
          for (int kk = 0; kk < 2; ++kk) {
            if (t < 4)
              acc2[m][n] = __builtin_amdgcn_mfma_f32_16x16x32_f16(ahi[m][2 * tl + kk], bf[n][kk], acc2[m][n], 0, 0, 0);
            else if (t < 8)
              acc2[m][n] = __builtin_amdgcn_mfma_f32_16x16x32_f16(alo[m][2 * tl + kk], bf[n][kk], acc2[m][n], 0, 0, 0);
            else
              acc[m][n] = __builtin_amdgcn_mfma_f32_16x16x32_f16(ahi[m][2 * tl + kk], bf[n][kk], acc[m][n], 0, 0, 0);
          }
    }
  }

#pragma unroll
  for (int m = 0; m < 2; ++m)
#pragma unroll
    for (int n = 0; n < 4; ++n) {
      const int ncol = n0 + wc * 64 + n * 16 + lj;
      const float bb = bias[ncol];
#pragma unroll
      for (int j = 0; j < 4; ++j) {
        const int tok = m0 + wr * 32 + m * 16 + li * 4 + j;
        const float vv = acc[m][n][j] + acc2[m][n][j] * LO_INV + bb;
        if (WEXT) {
          const f16 hh = (f16)vv;
          CextOut[(size_t)tok * 512 + ncol] = hh;
          CextOut[(size_t)tok * 512 + 256 + ncol] = (f16)((vv - (float)hh) * LO_SCALE);
        } else {
          Cout[(size_t)tok * Ntot + ncol] = vv;
        }
      }
    }
}

__global__ void zero_one(float* p) { p[0] = 0.f; }

__global__ void finalize_com(const float* __restrict__ a, float* __restrict__ o) {
  o[0] = a[0] * (1.0f / (float)((size_t)NQUANT * BT * DDIM));
}

extern "C" void kernel_launch(void* const* d_in, const int* in_sizes, int n_in,
                              void* d_out, int out_size, void* d_ws, size_t ws_size,
                              hipStream_t stream) {
  (void)in_sizes; (void)n_in; (void)out_size; (void)ws_size;
  const float* x     = (const float*)d_in[0];
  const float* W_in  = (const float*)d_in[1];
  const float* b_in  = (const float*)d_in[2];
  const float* W_out = (const float*)d_in[3];
  const float* b_out = (const float*)d_in[4];
  const float* cbs   = (const float*)d_in[5];

  float* out = (float*)d_out;                        // [BT, HIDDEN]
  float* q1  = out + (size_t)BT * HIDDEN;            // [BT, DDIM]
  float* q2  = q1 + (size_t)BT * DDIM;               // [BT, DDIM]
  float* com = q2 + (size_t)BT * DDIM;               // [1]

  f16*   rext      = (f16*)d_ws;                          // [BT][512]   32 MB
  float* qsum      = (float*)(rext + (size_t)BT * 512);   // [BT][256]   32 MB
  f16*   cbext     = (f16*)(qsum + (size_t)BT * DDIM);    // [8192][512]  8 MB
  f16*   W_inext   = cbext + (size_t)NQUANT * KCODE * 512; // [256][1024] 512 KB
  f16*   W_outext  = W_inext + (size_t)DDIM * 1024;        // [512][512]  512 KB
  float* cnorm     = (float*)(W_outext + (size_t)HIDDEN * 512);  // [NQ*K]
  float* commitAcc = cnorm + NQUANT * KCODE;

  cnorm_kernel<<<NQUANT * KCODE, 256, 0, stream>>>(cbs, cnorm);
  cbext_conv<<<NQUANT * KCODE, 256, 0, stream>>>(cbs, cbext);
  bext_conv<<<(DDIM * HIDDEN + 255) / 256, 256, 0, stream>>>(W_in, W_inext, DDIM, HIDDEN);
  bext_conv<<<(HIDDEN * DDIM + 255) / 256, 256, 0, stream>>>(W_out, W_outext, HIDDEN, DDIM);
  proj_mfma<HIDDEN, true><<<dim3(BT / 128, 2), 512, 0, stream>>>(
      x, W_inext, b_in, nullptr, rext, DDIM);
  zero_one<<<1, 1, 0, stream>>>(commitAcc);
  rvq_fused<<<BT / 128, 512, 0, stream>>>(rext, cbext, cbs, cnorm,
                                          qsum, q1, q2, commitAcc);
  proj_mfma<DDIM, false><<<dim3(BT / 128, 4), 512, 0, stream>>>(
      qsum, W_outext, b_out, out, nullptr, HIDDEN);
  finalize_com<<<1, 1, 0, stream>>>(commitAcc, com);
}